// Round 8
// baseline (322.441 us; speedup 1.0000x reference)
//
#include <hip/hip_runtime.h>
#include <hip/hip_bf16.h>
#include <hip/hip_fp16.h>

// GQNN: 2-layer GraphSAGE (mean aggr) + fc head. N=100k, E=3.2M, d=64/65.
// R8: quarter-wave gathers in aggr kernels. Wave = 4 quarters x 16 lanes;
// quarter g takes neighbor j+g, lane loads half4 (8B, 4 cols) => one gather
// instruction covers 4 rows (4 L2 lines; R7 showed 2 lines/instr is safe,
// R3 showed 8 collapses L2 — FETCH_SIZE is the canary). Neighbor indices
// read directly from colidx per-quarter (coalesced, L1) — zero ds_bpermute,
// so the DS round-trip leaves the dependency chain. ~2.3 instr/edge vs 3.2.
// GEMMs (MFMA, pre-swizzled B) and CSR build unchanged from R7.

#define WAVES_PER_BLOCK 16
#define LAYER_BLOCK (WAVES_PER_BLOCK * 64)
#define LAYER_GRID 512

#define BSH 7                    // bucket shift: 128 nodes per bucket
#define NBKT 782                 // ceil(100000 / 128)
#define NBLK 256                 // binning blocks

typedef _Float16 half8 __attribute__((ext_vector_type(8)));
typedef float floatx4 __attribute__((ext_vector_type(4)));

struct h4 { __half2 lo, hi; };   // 8B packed row chunk

// ---------------- CSR build (unchanged from R2) ----------------

__global__ __launch_bounds__(256) void k_hist(const int* __restrict__ dst,
                                              int* __restrict__ histT, int E) {
    __shared__ int h[NBKT];
    for (int i = threadIdx.x; i < NBKT; i += 256) h[i] = 0;
    __syncthreads();
    int per = (E + NBLK - 1) / NBLK;
    int lo = blockIdx.x * per;
    int hi = lo + per; if (hi > E) hi = E;
    for (int e = lo + threadIdx.x; e < hi; e += 256)
        atomicAdd(&h[dst[e] >> BSH], 1);
    __syncthreads();
    for (int k = threadIdx.x; k < NBKT; k += 256)
        histT[k * NBLK + blockIdx.x] = h[k];
}

__global__ __launch_bounds__(NBLK) void k_scanblk(int* __restrict__ histT,
                                                  int* __restrict__ btot) {
    __shared__ int s[NBLK];
    int k = blockIdx.x, t = threadIdx.x;
    int v = histT[k * NBLK + t];
    s[t] = v;
    __syncthreads();
    for (int off = 1; off < NBLK; off <<= 1) {
        int u = (t >= off) ? s[t - off] : 0;
        __syncthreads();
        s[t] += u;
        __syncthreads();
    }
    histT[k * NBLK + t] = s[t] - v;
    if (t == NBLK - 1) btot[k] = s[t];
}

__global__ __launch_bounds__(1024) void k_scanbkt(const int* __restrict__ btot,
                                                  int* __restrict__ bstart) {
    __shared__ int s[1024];
    int t = threadIdx.x;
    int v = (t < NBKT) ? btot[t] : 0;
    s[t] = v;
    __syncthreads();
    for (int off = 1; off < 1024; off <<= 1) {
        int u = (t >= off) ? s[t - off] : 0;
        __syncthreads();
        s[t] += u;
        __syncthreads();
    }
    if (t < NBKT) bstart[t] = s[t] - v;
    if (t == NBKT - 1) bstart[NBKT] = s[t];
}

__global__ __launch_bounds__(256) void k_scatter(const int* __restrict__ src,
                                                 const int* __restrict__ dst,
                                                 const int* __restrict__ histT,
                                                 const int* __restrict__ bstart,
                                                 int* __restrict__ binned, int E) {
    __shared__ int cur[NBKT];
    int b = blockIdx.x;
    for (int k = threadIdx.x; k < NBKT; k += 256)
        cur[k] = bstart[k] + histT[k * NBLK + b];
    __syncthreads();
    int per = (E + NBLK - 1) / NBLK;
    int lo = b * per;
    int hi = lo + per; if (hi > E) hi = E;
    for (int e = lo + threadIdx.x; e < hi; e += 256) {
        int d = dst[e], s = src[e];
        int pos = atomicAdd(&cur[d >> BSH], 1);
        binned[pos] = (s << BSH) | (d & ((1 << BSH) - 1));
    }
}

__global__ __launch_bounds__(256) void k_bucket(const int* __restrict__ binned,
                                                const int* __restrict__ bstart,
                                                int* __restrict__ rowptr,
                                                int* __restrict__ deg,
                                                int* __restrict__ colidx, int N) {
    __shared__ int cnt[128], sc[128], cur[128];
    int k = blockIdx.x, t = threadIdx.x;
    int lo = bstart[k], hi = bstart[k + 1];
    if (t < 128) cnt[t] = 0;
    __syncthreads();
    for (int e = lo + t; e < hi; e += 256)
        atomicAdd(&cnt[binned[e] & 127], 1);
    __syncthreads();
    if (t < 128) sc[t] = cnt[t];
    __syncthreads();
    for (int off = 1; off < 128; off <<= 1) {
        int u = 0;
        if (t < 128 && t >= off) u = sc[t - off];
        __syncthreads();
        if (t < 128) sc[t] += u;
        __syncthreads();
    }
    if (t < 128) {
        int abs0 = lo + (sc[t] - cnt[t]);
        cur[t] = abs0;
        int gnode = (k << BSH) + t;
        if (gnode < N) { rowptr[gnode] = abs0; deg[gnode] = cnt[t]; }
    }
    __syncthreads();
    for (int e = lo + t; e < hi; e += 256) {
        int p = binned[e];
        int pos = atomicAdd(&cur[p & 127], 1);
        colidx[pos] = p >> BSH;
    }
}

// ---------------- fp32 -> fp16 prep for x ----------------
__global__ __launch_bounds__(256) void k_prep(const float* __restrict__ x,
                                              __half* __restrict__ xh, int n2) {
    int i = blockIdx.x * 256 + threadIdx.x;
    if (i < n2) {
        float2 v = ((const float2*)x)[i];
        ((__half2*)xh)[i] = __floats2half2_rn(v.x, v.y);
    }
}

// ---------------- W -> fp16 B-fragment swizzle (unchanged from R7) ----------
__global__ __launch_bounds__(256) void k_prepw(
    const float* __restrict__ W1l, const float* __restrict__ W1r,
    const float* __restrict__ W2l, const float* __restrict__ W2r,
    __half* __restrict__ wbuf1, __half* __restrict__ wbuf2) {
    int idx = blockIdx.x * 256 + threadIdx.x;
    if (idx < 1280) {
        int lane = idx & 63;
        int nt = (idx >> 6) & 3;
        int kstep = idx >> 8;
        int col = nt * 16 + (lane & 15);
        int kbase = kstep * 32 + (lane >> 4) * 8;
#pragma unroll
        for (int j = 0; j < 8; ++j) {
            int k = kbase + j;
            float v;
            if (k < 64)       v = W1l[k * 64 + col];
            else if (k < 128) v = W1r[(k - 64) * 64 + col];
            else if (k == 128) v = W1l[64 * 64 + col];
            else if (k == 129) v = W1r[64 * 64 + col];
            else v = 0.f;
            wbuf1[(size_t)idx * 8 + j] = __float2half(v);
        }
    } else if (idx < 1280 + 1024) {
        int i2 = idx - 1280;
        int lane = i2 & 63;
        int nt = (i2 >> 6) & 3;
        int kstep = i2 >> 8;
        int col = nt * 16 + (lane & 15);
        int kbase = kstep * 32 + (lane >> 4) * 8;
#pragma unroll
        for (int j = 0; j < 8; ++j) {
            int k = kbase + j;
            float v = (k < 64) ? W2l[k * 64 + col] : W2r[(k - 64) * 64 + col];
            wbuf2[(size_t)i2 * 8 + j] = __float2half(v);
        }
    }
}

// ---------------- Aggregation (R8: quarter-wave half4 gathers) ----------------
// grp = lane>>4 takes neighbor j+grp; c4 = lane&15 covers cols [4c4, 4c4+4).
// One gather instruction = 4 rows x 128B. Indices read straight from colidx
// (16 lanes share one address -> coalesced broadcast, L1-hit).

__device__ __forceinline__ void acc_h4(float4& A, h4 r) {
    float2 f0 = __half22float2(r.lo);
    float2 f1 = __half22float2(r.hi);
    A.x += f0.x; A.y += f0.y; A.z += f1.x; A.w += f1.y;
}

// zm1[node][64] = mean_x (fp16); mt1[node] = mean_tau (fp16)
__global__ __launch_bounds__(LAYER_BLOCK) void k_aggr1(
    const __half* __restrict__ xh, const float* __restrict__ tau,
    const int* __restrict__ rowptr, const int* __restrict__ deg,
    const int* __restrict__ colidx,
    __half* __restrict__ zm1, __half* __restrict__ mt1, int N) {
    int lane = threadIdx.x & 63;
    int grp = lane >> 4;
    int c4 = lane & 15;
    int wave = blockIdx.x * WAVES_PER_BLOCK + (threadIdx.x >> 6);
    int nwaves = gridDim.x * WAVES_PER_BLOCK;

    for (int node = wave; node < N; node += nwaves) {
        int start = rowptr[node];
        int d = deg[node];
        float4 A0 = {0.f, 0.f, 0.f, 0.f};
        float4 A1 = {0.f, 0.f, 0.f, 0.f};
        float sumtau = 0.f;
        // tau sum (random scalar gather, one pass)
        for (int t = lane; t < d; t += 64) sumtau += tau[colidx[start + t]];
        // main gather: 8 neighbors per iteration, 2 independent accumulators
        int j = 0;
        for (; j + 8 <= d; j += 8) {
            int i0 = colidx[start + j + grp];
            int i1 = colidx[start + j + 4 + grp];
            h4 r0 = *(const h4*)(xh + ((size_t)(unsigned)i0 << 6) + (c4 << 2));
            h4 r1 = *(const h4*)(xh + ((size_t)(unsigned)i1 << 6) + (c4 << 2));
            acc_h4(A0, r0);
            acc_h4(A1, r1);
        }
        for (; j < d; j += 4) {
            int jj = j + grp;
            if (jj < d) {
                int i0 = colidx[start + jj];
                h4 r0 = *(const h4*)(xh + ((size_t)(unsigned)i0 << 6) + (c4 << 2));
                acc_h4(A0, r0);
            }
        }
        A0.x += A1.x; A0.y += A1.y; A0.z += A1.z; A0.w += A1.w;
#pragma unroll
        for (int m = 16; m <= 32; m <<= 1) {
            A0.x += __shfl_xor(A0.x, m, 64);
            A0.y += __shfl_xor(A0.y, m, 64);
            A0.z += __shfl_xor(A0.z, m, 64);
            A0.w += __shfl_xor(A0.w, m, 64);
        }
#pragma unroll
        for (int off = 32; off > 0; off >>= 1) sumtau += __shfl_down(sumtau, off, 64);

        float inv = 1.f / fmaxf((float)d, 1.f);
        if (lane < 16) {
            h4 o;
            o.lo = __floats2half2_rn(A0.x * inv, A0.y * inv);
            o.hi = __floats2half2_rn(A0.z * inv, A0.w * inv);
            *(h4*)(zm1 + (size_t)node * 64 + (c4 << 2)) = o;
        }
        if (lane == 0) mt1[node] = __float2half(sumtau * inv);
    }
}

// zm2[node][64] = mean_h1 (fp16)
__global__ __launch_bounds__(LAYER_BLOCK) void k_aggr2(
    const __half* __restrict__ h1,
    const int* __restrict__ rowptr, const int* __restrict__ deg,
    const int* __restrict__ colidx, __half* __restrict__ zm2, int N) {
    int lane = threadIdx.x & 63;
    int grp = lane >> 4;
    int c4 = lane & 15;
    int wave = blockIdx.x * WAVES_PER_BLOCK + (threadIdx.x >> 6);
    int nwaves = gridDim.x * WAVES_PER_BLOCK;

    for (int node = wave; node < N; node += nwaves) {
        int start = rowptr[node];
        int d = deg[node];
        float4 A0 = {0.f, 0.f, 0.f, 0.f};
        float4 A1 = {0.f, 0.f, 0.f, 0.f};
        int j = 0;
        for (; j + 8 <= d; j += 8) {
            int i0 = colidx[start + j + grp];
            int i1 = colidx[start + j + 4 + grp];
            h4 r0 = *(const h4*)(h1 + ((size_t)(unsigned)i0 << 6) + (c4 << 2));
            h4 r1 = *(const h4*)(h1 + ((size_t)(unsigned)i1 << 6) + (c4 << 2));
            acc_h4(A0, r0);
            acc_h4(A1, r1);
        }
        for (; j < d; j += 4) {
            int jj = j + grp;
            if (jj < d) {
                int i0 = colidx[start + jj];
                h4 r0 = *(const h4*)(h1 + ((size_t)(unsigned)i0 << 6) + (c4 << 2));
                acc_h4(A0, r0);
            }
        }
        A0.x += A1.x; A0.y += A1.y; A0.z += A1.z; A0.w += A1.w;
#pragma unroll
        for (int m = 16; m <= 32; m <<= 1) {
            A0.x += __shfl_xor(A0.x, m, 64);
            A0.y += __shfl_xor(A0.y, m, 64);
            A0.z += __shfl_xor(A0.z, m, 64);
            A0.w += __shfl_xor(A0.w, m, 64);
        }
        float inv = 1.f / fmaxf((float)d, 1.f);
        if (lane < 16) {
            h4 o;
            o.lo = __floats2half2_rn(A0.x * inv, A0.y * inv);
            o.hi = __floats2half2_rn(A0.z * inv, A0.w * inv);
            *(h4*)(zm2 + (size_t)node * 64 + (c4 << 2)) = o;
        }
    }
}

// ---------------- MFMA GEMM kernels (unchanged from R7) ----------------

__global__ __launch_bounds__(256) void k_gemm1(
    const __half* __restrict__ zm1, const __half* __restrict__ mt1,
    const __half* __restrict__ xh, const float* __restrict__ tau,
    const __half* __restrict__ wbuf1, const float* __restrict__ b1l,
    __half* __restrict__ h1, int ntiles) {
    int tile = blockIdx.x * 4 + (threadIdx.x >> 6);
    if (tile >= ntiles) return;
    int lane = threadIdx.x & 63;
    int sub = lane & 15;
    int quad = lane >> 4;
    int row = tile * 16 + sub;

    floatx4 acc0 = {0.f, 0.f, 0.f, 0.f};
    floatx4 acc1 = {0.f, 0.f, 0.f, 0.f};
    floatx4 acc2 = {0.f, 0.f, 0.f, 0.f};
    floatx4 acc3 = {0.f, 0.f, 0.f, 0.f};

    const _Float16* zrow = (const _Float16*)zm1 + (size_t)row * 64 + quad * 8;
    const _Float16* xrow = (const _Float16*)xh + (size_t)row * 64 + quad * 8;
    const _Float16* wb = (const _Float16*)wbuf1 + (size_t)lane * 8;

    half8 amat[5];
    amat[0] = *(const half8*)(zrow);
    amat[1] = *(const half8*)(zrow + 32);
    amat[2] = *(const half8*)(xrow);
    amat[3] = *(const half8*)(xrow + 32);
    half8 a4 = {0, 0, 0, 0, 0, 0, 0, 0};
    if (quad == 0) {
        a4[0] = ((const _Float16*)mt1)[row];
        a4[1] = (_Float16)tau[row];
    }
    amat[4] = a4;

#pragma unroll
    for (int ks = 0; ks < 5; ++ks) {
        half8 a = amat[ks];
        half8 b0 = *(const half8*)(wb + (size_t)(ks * 4 + 0) * 512);
        half8 b1 = *(const half8*)(wb + (size_t)(ks * 4 + 1) * 512);
        half8 b2 = *(const half8*)(wb + (size_t)(ks * 4 + 2) * 512);
        half8 b3 = *(const half8*)(wb + (size_t)(ks * 4 + 3) * 512);
        acc0 = __builtin_amdgcn_mfma_f32_16x16x32_f16(a, b0, acc0, 0, 0, 0);
        acc1 = __builtin_amdgcn_mfma_f32_16x16x32_f16(a, b1, acc1, 0, 0, 0);
        acc2 = __builtin_amdgcn_mfma_f32_16x16x32_f16(a, b2, acc2, 0, 0, 0);
        acc3 = __builtin_amdgcn_mfma_f32_16x16x32_f16(a, b3, acc3, 0, 0, 0);
    }
    float bv0 = b1l[sub], bv1 = b1l[16 + sub], bv2 = b1l[32 + sub], bv3 = b1l[48 + sub];
#pragma unroll
    for (int reg = 0; reg < 4; ++reg) {
        int r = quad * 4 + reg;
        __half* orow = h1 + (size_t)(tile * 16 + r) * 64;
        orow[sub]      = __float2half(fmaxf(acc0[reg] + bv0, 0.f));
        orow[16 + sub] = __float2half(fmaxf(acc1[reg] + bv1, 0.f));
        orow[32 + sub] = __float2half(fmaxf(acc2[reg] + bv2, 0.f));
        orow[48 + sub] = __float2half(fmaxf(acc3[reg] + bv3, 0.f));
    }
}

__global__ __launch_bounds__(256) void k_gemm2(
    const __half* __restrict__ zm2, const __half* __restrict__ h1,
    const __half* __restrict__ wbuf2, const float* __restrict__ b2l,
    const float* __restrict__ Wfc, const float* __restrict__ bfc,
    float* __restrict__ out, int ntiles) {
    int tile = blockIdx.x * 4 + (threadIdx.x >> 6);
    if (tile >= ntiles) return;
    int lane = threadIdx.x & 63;
    int sub = lane & 15;
    int quad = lane >> 4;
    int row = tile * 16 + sub;

    floatx4 acc0 = {0.f, 0.f, 0.f, 0.f};
    floatx4 acc1 = {0.f, 0.f, 0.f, 0.f};
    floatx4 acc2 = {0.f, 0.f, 0.f, 0.f};
    floatx4 acc3 = {0.f, 0.f, 0.f, 0.f};

    const _Float16* zrow = (const _Float16*)zm2 + (size_t)row * 64 + quad * 8;
    const _Float16* hrow = (const _Float16*)h1 + (size_t)row * 64 + quad * 8;
    const _Float16* wb = (const _Float16*)wbuf2 + (size_t)lane * 8;

    half8 amat[4];
    amat[0] = *(const half8*)(zrow);
    amat[1] = *(const half8*)(zrow + 32);
    amat[2] = *(const half8*)(hrow);
    amat[3] = *(const half8*)(hrow + 32);

#pragma unroll
    for (int ks = 0; ks < 4; ++ks) {
        half8 a = amat[ks];
        half8 b0 = *(const half8*)(wb + (size_t)(ks * 4 + 0) * 512);
        half8 b1 = *(const half8*)(wb + (size_t)(ks * 4 + 1) * 512);
        half8 b2 = *(const half8*)(wb + (size_t)(ks * 4 + 2) * 512);
        half8 b3 = *(const half8*)(wb + (size_t)(ks * 4 + 3) * 512);
        acc0 = __builtin_amdgcn_mfma_f32_16x16x32_f16(a, b0, acc0, 0, 0, 0);
        acc1 = __builtin_amdgcn_mfma_f32_16x16x32_f16(a, b1, acc1, 0, 0, 0);
        acc2 = __builtin_amdgcn_mfma_f32_16x16x32_f16(a, b2, acc2, 0, 0, 0);
        acc3 = __builtin_amdgcn_mfma_f32_16x16x32_f16(a, b3, acc3, 0, 0, 0);
    }
    float bb0 = b2l[sub], bb1 = b2l[16 + sub], bb2 = b2l[32 + sub], bb3 = b2l[48 + sub];
    float wv0 = Wfc[sub], wv1 = Wfc[16 + sub], wv2 = Wfc[32 + sub], wv3 = Wfc[48 + sub];
    float p[4];
#pragma unroll
    for (int reg = 0; reg < 4; ++reg) {
        p[reg] = fmaxf(acc0[reg] + bb0, 0.f) * wv0
               + fmaxf(acc1[reg] + bb1, 0.f) * wv1
               + fmaxf(acc2[reg] + bb2, 0.f) * wv2
               + fmaxf(acc3[reg] + bb3, 0.f) * wv3;
    }
#pragma unroll
    for (int m = 1; m <= 8; m <<= 1) {
#pragma unroll
        for (int reg = 0; reg < 4; ++reg) p[reg] += __shfl_xor(p[reg], m, 64);
    }
    if (sub == 0) {
        float b0 = bfc[0];
#pragma unroll
        for (int reg = 0; reg < 4; ++reg)
            out[tile * 16 + quad * 4 + reg] = p[reg] + b0;
    }
}

extern "C" void kernel_launch(void* const* d_in, const int* in_sizes, int n_in,
                              void* d_out, int out_size, void* d_ws, size_t ws_size,
                              hipStream_t stream) {
    const float* x   = (const float*)d_in[0];
    const int*   ei  = (const int*)d_in[1];
    const float* tau = (const float*)d_in[2];
    const float* W1l = (const float*)d_in[3];
    const float* b1l = (const float*)d_in[4];
    const float* W1r = (const float*)d_in[5];
    const float* W2l = (const float*)d_in[6];
    const float* b2l = (const float*)d_in[7];
    const float* W2r = (const float*)d_in[8];
    const float* Wfc = (const float*)d_in[9];
    const float* bfc = (const float*)d_in[10];
    float* out = (float*)d_out;

    const int N = in_sizes[0] / 64;   // 100000
    const int E = in_sizes[1] / 2;    // 3200000
    const int* src = ei;
    const int* dst = ei + E;

    char* w = (char*)d_ws;
    auto take = [&](size_t b) { char* p = w; w += (b + 255) & ~(size_t)255; return p; };
    int*    histT  = (int*)take((size_t)NBKT * NBLK * 4);
    int*    btot   = (int*)take((size_t)NBKT * 4);
    int*    bstart = (int*)take((size_t)(NBKT + 1) * 4);
    int*    binned = (int*)take((size_t)E * 4);
    int*    rowptr = (int*)take((size_t)N * 4);
    int*    deg    = (int*)take((size_t)N * 4);
    int*    colidx = (int*)take((size_t)E * 4);
    __half* xh     = (__half*)take((size_t)N * 64 * 2);    // 12.8 MB
    __half* h1     = (__half*)take((size_t)N * 64 * 2);    // 12.8 MB
    __half* zm1    = (__half*)take((size_t)N * 64 * 2);    // 12.8 MB
    __half* mt1    = (__half*)take((size_t)N * 2);
    __half* zm2    = (__half*)take((size_t)N * 64 * 2);    // 12.8 MB
    __half* wbuf1  = (__half*)take(1280 * 8 * 2);          // 20 KB
    __half* wbuf2  = (__half*)take(1024 * 8 * 2);          // 16 KB

    int n2 = N * 32;                  // half2 elements for prep
    int ntiles = N / 16;              // 6250 (exact)
    int gblocks = (ntiles + 3) / 4;   // 1563

    k_hist   <<<NBLK, 256, 0, stream>>>(dst, histT, E);
    k_scanblk<<<NBKT, NBLK, 0, stream>>>(histT, btot);
    k_scanbkt<<<1, 1024, 0, stream>>>(btot, bstart);
    k_scatter<<<NBLK, 256, 0, stream>>>(src, dst, histT, bstart, binned, E);
    k_bucket <<<NBKT, 256, 0, stream>>>(binned, bstart, rowptr, deg, colidx, N);
    k_prep   <<<(n2 + 255) / 256, 256, 0, stream>>>(x, xh, n2);
    k_prepw  <<<9, 256, 0, stream>>>(W1l, W1r, W2l, W2r, wbuf1, wbuf2);
    k_aggr1  <<<LAYER_GRID, LAYER_BLOCK, 0, stream>>>(xh, tau, rowptr, deg, colidx, zm1, mt1, N);
    k_gemm1  <<<gblocks, 256, 0, stream>>>(zm1, mt1, xh, tau, wbuf1, b1l, h1, ntiles);
    k_aggr2  <<<LAYER_GRID, LAYER_BLOCK, 0, stream>>>(h1, rowptr, deg, colidx, zm2, N);
    k_gemm2  <<<gblocks, 256, 0, stream>>>(zm2, h1, wbuf2, b2l, Wfc, bfc, out, ntiles);
}

// Round 9
// 305.793 us; speedup vs baseline: 1.0544x; 1.0544x over previous
//
#include <hip/hip_runtime.h>
#include <hip/hip_bf16.h>
#include <hip/hip_fp16.h>

// GQNN: 2-layer GraphSAGE (mean aggr) + fc head. N=100k, E=3.2M, d=64/65.
// R9: two-nodes-per-wave aggregation. R8 (quarter-wave, 4 rows/instr)
// regressed 63->73us; R7 full-wave pair shape reverted and improved:
// lanes 0-31 = node A, lanes 32-63 = node B; one bpermute + one half2
// gather instruction serves one neighbor of EACH node (2 independent
// dependency chains), no cross-half fold, dynamic inner bound max(dA,dB).
// prep+prepw fused (-1 launch). GEMMs (MFMA) + CSR build unchanged.

#define WAVES_PER_BLOCK 16
#define LAYER_BLOCK (WAVES_PER_BLOCK * 64)
#define LAYER_GRID 512

#define BSH 7                    // bucket shift: 128 nodes per bucket
#define NBKT 782                 // ceil(100000 / 128)
#define NBLK 256                 // binning blocks

typedef _Float16 half8 __attribute__((ext_vector_type(8)));
typedef float floatx4 __attribute__((ext_vector_type(4)));

// ---------------- CSR build (unchanged from R2) ----------------

__global__ __launch_bounds__(256) void k_hist(const int* __restrict__ dst,
                                              int* __restrict__ histT, int E) {
    __shared__ int h[NBKT];
    for (int i = threadIdx.x; i < NBKT; i += 256) h[i] = 0;
    __syncthreads();
    int per = (E + NBLK - 1) / NBLK;
    int lo = blockIdx.x * per;
    int hi = lo + per; if (hi > E) hi = E;
    for (int e = lo + threadIdx.x; e < hi; e += 256)
        atomicAdd(&h[dst[e] >> BSH], 1);
    __syncthreads();
    for (int k = threadIdx.x; k < NBKT; k += 256)
        histT[k * NBLK + blockIdx.x] = h[k];
}

__global__ __launch_bounds__(NBLK) void k_scanblk(int* __restrict__ histT,
                                                  int* __restrict__ btot) {
    __shared__ int s[NBLK];
    int k = blockIdx.x, t = threadIdx.x;
    int v = histT[k * NBLK + t];
    s[t] = v;
    __syncthreads();
    for (int off = 1; off < NBLK; off <<= 1) {
        int u = (t >= off) ? s[t - off] : 0;
        __syncthreads();
        s[t] += u;
        __syncthreads();
    }
    histT[k * NBLK + t] = s[t] - v;
    if (t == NBLK - 1) btot[k] = s[t];
}

__global__ __launch_bounds__(1024) void k_scanbkt(const int* __restrict__ btot,
                                                  int* __restrict__ bstart) {
    __shared__ int s[1024];
    int t = threadIdx.x;
    int v = (t < NBKT) ? btot[t] : 0;
    s[t] = v;
    __syncthreads();
    for (int off = 1; off < 1024; off <<= 1) {
        int u = (t >= off) ? s[t - off] : 0;
        __syncthreads();
        s[t] += u;
        __syncthreads();
    }
    if (t < NBKT) bstart[t] = s[t] - v;
    if (t == NBKT - 1) bstart[NBKT] = s[t];
}

__global__ __launch_bounds__(256) void k_scatter(const int* __restrict__ src,
                                                 const int* __restrict__ dst,
                                                 const int* __restrict__ histT,
                                                 const int* __restrict__ bstart,
                                                 int* __restrict__ binned, int E) {
    __shared__ int cur[NBKT];
    int b = blockIdx.x;
    for (int k = threadIdx.x; k < NBKT; k += 256)
        cur[k] = bstart[k] + histT[k * NBLK + b];
    __syncthreads();
    int per = (E + NBLK - 1) / NBLK;
    int lo = b * per;
    int hi = lo + per; if (hi > E) hi = E;
    for (int e = lo + threadIdx.x; e < hi; e += 256) {
        int d = dst[e], s = src[e];
        int pos = atomicAdd(&cur[d >> BSH], 1);
        binned[pos] = (s << BSH) | (d & ((1 << BSH) - 1));
    }
}

__global__ __launch_bounds__(256) void k_bucket(const int* __restrict__ binned,
                                                const int* __restrict__ bstart,
                                                int* __restrict__ rowptr,
                                                int* __restrict__ deg,
                                                int* __restrict__ colidx, int N) {
    __shared__ int cnt[128], sc[128], cur[128];
    int k = blockIdx.x, t = threadIdx.x;
    int lo = bstart[k], hi = bstart[k + 1];
    if (t < 128) cnt[t] = 0;
    __syncthreads();
    for (int e = lo + t; e < hi; e += 256)
        atomicAdd(&cnt[binned[e] & 127], 1);
    __syncthreads();
    if (t < 128) sc[t] = cnt[t];
    __syncthreads();
    for (int off = 1; off < 128; off <<= 1) {
        int u = 0;
        if (t < 128 && t >= off) u = sc[t - off];
        __syncthreads();
        if (t < 128) sc[t] += u;
        __syncthreads();
    }
    if (t < 128) {
        int abs0 = lo + (sc[t] - cnt[t]);
        cur[t] = abs0;
        int gnode = (k << BSH) + t;
        if (gnode < N) { rowptr[gnode] = abs0; deg[gnode] = cnt[t]; }
    }
    __syncthreads();
    for (int e = lo + t; e < hi; e += 256) {
        int p = binned[e];
        int pos = atomicAdd(&cur[p & 127], 1);
        colidx[pos] = p >> BSH;
    }
}

// ---------------- fused prep: x->fp16  +  W->B-fragment swizzle ----------------
// blocks 0..8: weight swizzle (2304 work items). blocks 9..: x conversion.
__global__ __launch_bounds__(256) void k_prepall(
    const float* __restrict__ x, __half* __restrict__ xh, int n2,
    const float* __restrict__ W1l, const float* __restrict__ W1r,
    const float* __restrict__ W2l, const float* __restrict__ W2r,
    __half* __restrict__ wbuf1, __half* __restrict__ wbuf2) {
    if (blockIdx.x < 9) {
        int idx = blockIdx.x * 256 + threadIdx.x;
        if (idx < 1280) {
            int lane = idx & 63;
            int nt = (idx >> 6) & 3;
            int kstep = idx >> 8;
            int col = nt * 16 + (lane & 15);
            int kbase = kstep * 32 + (lane >> 4) * 8;
#pragma unroll
            for (int j = 0; j < 8; ++j) {
                int k = kbase + j;
                float v;
                if (k < 64)        v = W1l[k * 64 + col];
                else if (k < 128)  v = W1r[(k - 64) * 64 + col];
                else if (k == 128) v = W1l[64 * 64 + col];
                else if (k == 129) v = W1r[64 * 64 + col];
                else v = 0.f;
                wbuf1[(size_t)idx * 8 + j] = __float2half(v);
            }
        } else if (idx < 1280 + 1024) {
            int i2 = idx - 1280;
            int lane = i2 & 63;
            int nt = (i2 >> 6) & 3;
            int kstep = i2 >> 8;
            int col = nt * 16 + (lane & 15);
            int kbase = kstep * 32 + (lane >> 4) * 8;
#pragma unroll
            for (int j = 0; j < 8; ++j) {
                int k = kbase + j;
                float v = (k < 64) ? W2l[k * 64 + col] : W2r[(k - 64) * 64 + col];
                wbuf2[(size_t)i2 * 8 + j] = __float2half(v);
            }
        }
    } else {
        int i = (blockIdx.x - 9) * 256 + threadIdx.x;
        if (i < n2) {
            float2 v = ((const float2*)x)[i];
            ((__half2*)xh)[i] = __floats2half2_rn(v.x, v.y);
        }
    }
}

// ---------------- Aggregation (R9: two nodes per wave) ----------------
// half = lane>>5 selects node (A: lanes 0-31, B: 32-63); c = lane&31 covers
// cols {2c, 2c+1} via one half2. One bpermute + one gather instruction
// processes one neighbor of EACH node => 2 independent chains, no cross-fold.

// zm1[node][64] = mean_x (fp16); mt1[node] = mean_tau (fp16)
__global__ __launch_bounds__(LAYER_BLOCK) void k_aggr1(
    const __half* __restrict__ xh, const float* __restrict__ tau,
    const int* __restrict__ rowptr, const int* __restrict__ deg,
    const int* __restrict__ colidx,
    __half* __restrict__ zm1, __half* __restrict__ mt1, int N) {
    int lane = threadIdx.x & 63;
    int half = lane >> 5;
    int c = lane & 31;
    int wave = blockIdx.x * WAVES_PER_BLOCK + (threadIdx.x >> 6);
    int nwaves = gridDim.x * WAVES_PER_BLOCK;
    int npairs = N >> 1;   // N even

    for (int pair = wave; pair < npairs; pair += nwaves) {
        int node = pair * 2 + half;          // per-half node
        int start = rowptr[node];
        int d = deg[node];
        float2 A0 = {0.f, 0.f}, A1 = {0.f, 0.f}, A2 = {0.f, 0.f}, A3 = {0.f, 0.f};
        float sumtau = 0.f;
        for (int base = 0; base < d || base < __shfl_xor(d, 32, 64); base += 32) {
            int n = d - base;
            n = (n < 0) ? 0 : (n > 32 ? 32 : n);
            int nmax = max(n, __shfl_xor(n, 32, 64));   // uniform across wave
            int sidx = 0;
            if (c < n) {
                sidx = colidx[start + base + c];
                sumtau += tau[sidx];
            }
            int j = 0;
            for (; j + 4 <= nmax; j += 4) {
                int i0 = __builtin_amdgcn_ds_bpermute((half * 32 + j + 0) << 2, sidx);
                int i1 = __builtin_amdgcn_ds_bpermute((half * 32 + j + 1) << 2, sidx);
                int i2 = __builtin_amdgcn_ds_bpermute((half * 32 + j + 2) << 2, sidx);
                int i3 = __builtin_amdgcn_ds_bpermute((half * 32 + j + 3) << 2, sidx);
                float2 v0 = __half22float2(*(const __half2*)(xh + ((size_t)(unsigned)i0 << 6) + (c << 1)));
                float2 v1 = __half22float2(*(const __half2*)(xh + ((size_t)(unsigned)i1 << 6) + (c << 1)));
                float2 v2 = __half22float2(*(const __half2*)(xh + ((size_t)(unsigned)i2 << 6) + (c << 1)));
                float2 v3 = __half22float2(*(const __half2*)(xh + ((size_t)(unsigned)i3 << 6) + (c << 1)));
                if (j + 0 < n) { A0.x += v0.x; A0.y += v0.y; }
                if (j + 1 < n) { A1.x += v1.x; A1.y += v1.y; }
                if (j + 2 < n) { A2.x += v2.x; A2.y += v2.y; }
                if (j + 3 < n) { A3.x += v3.x; A3.y += v3.y; }
            }
            for (; j < nmax; ++j) {
                int i0 = __builtin_amdgcn_ds_bpermute((half * 32 + j) << 2, sidx);
                float2 v0 = __half22float2(*(const __half2*)(xh + ((size_t)(unsigned)i0 << 6) + (c << 1)));
                if (j < n) { A0.x += v0.x; A0.y += v0.y; }
            }
        }
        float2 A;
        A.x = (A0.x + A1.x) + (A2.x + A3.x);
        A.y = (A0.y + A1.y) + (A2.y + A3.y);
#pragma unroll
        for (int off = 16; off > 0; off >>= 1) sumtau += __shfl_xor(sumtau, off, 64);

        float inv = 1.f / fmaxf((float)d, 1.f);
        ((__half2*)(zm1 + (size_t)node * 64))[c] = __floats2half2_rn(A.x * inv, A.y * inv);
        if (c == 0) mt1[node] = __float2half(sumtau * inv);
    }
}

// zm2[node][64] = mean_h1 (fp16)
__global__ __launch_bounds__(LAYER_BLOCK) void k_aggr2(
    const __half* __restrict__ h1,
    const int* __restrict__ rowptr, const int* __restrict__ deg,
    const int* __restrict__ colidx, __half* __restrict__ zm2, int N) {
    int lane = threadIdx.x & 63;
    int half = lane >> 5;
    int c = lane & 31;
    int wave = blockIdx.x * WAVES_PER_BLOCK + (threadIdx.x >> 6);
    int nwaves = gridDim.x * WAVES_PER_BLOCK;
    int npairs = N >> 1;

    for (int pair = wave; pair < npairs; pair += nwaves) {
        int node = pair * 2 + half;
        int start = rowptr[node];
        int d = deg[node];
        float2 A0 = {0.f, 0.f}, A1 = {0.f, 0.f}, A2 = {0.f, 0.f}, A3 = {0.f, 0.f};
        for (int base = 0; base < d || base < __shfl_xor(d, 32, 64); base += 32) {
            int n = d - base;
            n = (n < 0) ? 0 : (n > 32 ? 32 : n);
            int nmax = max(n, __shfl_xor(n, 32, 64));
            int sidx = 0;
            if (c < n) sidx = colidx[start + base + c];
            int j = 0;
            for (; j + 4 <= nmax; j += 4) {
                int i0 = __builtin_amdgcn_ds_bpermute((half * 32 + j + 0) << 2, sidx);
                int i1 = __builtin_amdgcn_ds_bpermute((half * 32 + j + 1) << 2, sidx);
                int i2 = __builtin_amdgcn_ds_bpermute((half * 32 + j + 2) << 2, sidx);
                int i3 = __builtin_amdgcn_ds_bpermute((half * 32 + j + 3) << 2, sidx);
                float2 v0 = __half22float2(*(const __half2*)(h1 + ((size_t)(unsigned)i0 << 6) + (c << 1)));
                float2 v1 = __half22float2(*(const __half2*)(h1 + ((size_t)(unsigned)i1 << 6) + (c << 1)));
                float2 v2 = __half22float2(*(const __half2*)(h1 + ((size_t)(unsigned)i2 << 6) + (c << 1)));
                float2 v3 = __half22float2(*(const __half2*)(h1 + ((size_t)(unsigned)i3 << 6) + (c << 1)));
                if (j + 0 < n) { A0.x += v0.x; A0.y += v0.y; }
                if (j + 1 < n) { A1.x += v1.x; A1.y += v1.y; }
                if (j + 2 < n) { A2.x += v2.x; A2.y += v2.y; }
                if (j + 3 < n) { A3.x += v3.x; A3.y += v3.y; }
            }
            for (; j < nmax; ++j) {
                int i0 = __builtin_amdgcn_ds_bpermute((half * 32 + j) << 2, sidx);
                float2 v0 = __half22float2(*(const __half2*)(h1 + ((size_t)(unsigned)i0 << 6) + (c << 1)));
                if (j < n) { A0.x += v0.x; A0.y += v0.y; }
            }
        }
        float2 A;
        A.x = (A0.x + A1.x) + (A2.x + A3.x);
        A.y = (A0.y + A1.y) + (A2.y + A3.y);
        float inv = 1.f / fmaxf((float)d, 1.f);
        ((__half2*)(zm2 + (size_t)node * 64))[c] = __floats2half2_rn(A.x * inv, A.y * inv);
    }
}

// ---------------- MFMA GEMM kernels (unchanged from R7) ----------------

__global__ __launch_bounds__(256) void k_gemm1(
    const __half* __restrict__ zm1, const __half* __restrict__ mt1,
    const __half* __restrict__ xh, const float* __restrict__ tau,
    const __half* __restrict__ wbuf1, const float* __restrict__ b1l,
    __half* __restrict__ h1, int ntiles) {
    int tile = blockIdx.x * 4 + (threadIdx.x >> 6);
    if (tile >= ntiles) return;
    int lane = threadIdx.x & 63;
    int sub = lane & 15;
    int quad = lane >> 4;
    int row = tile * 16 + sub;

    floatx4 acc0 = {0.f, 0.f, 0.f, 0.f};
    floatx4 acc1 = {0.f, 0.f, 0.f, 0.f};
    floatx4 acc2 = {0.f, 0.f, 0.f, 0.f};
    floatx4 acc3 = {0.f, 0.f, 0.f, 0.f};

    const _Float16* zrow = (const _Float16*)zm1 + (size_t)row * 64 + quad * 8;
    const _Float16* xrow = (const _Float16*)xh + (size_t)row * 64 + quad * 8;
    const _Float16* wb = (const _Float16*)wbuf1 + (size_t)lane * 8;

    half8 amat[5];
    amat[0] = *(const half8*)(zrow);
    amat[1] = *(const half8*)(zrow + 32);
    amat[2] = *(const half8*)(xrow);
    amat[3] = *(const half8*)(xrow + 32);
    half8 a4 = {0, 0, 0, 0, 0, 0, 0, 0};
    if (quad == 0) {
        a4[0] = ((const _Float16*)mt1)[row];
        a4[1] = (_Float16)tau[row];
    }
    amat[4] = a4;

#pragma unroll
    for (int ks = 0; ks < 5; ++ks) {
        half8 a = amat[ks];
        half8 b0 = *(const half8*)(wb + (size_t)(ks * 4 + 0) * 512);
        half8 b1 = *(const half8*)(wb + (size_t)(ks * 4 + 1) * 512);
        half8 b2 = *(const half8*)(wb + (size_t)(ks * 4 + 2) * 512);
        half8 b3 = *(const half8*)(wb + (size_t)(ks * 4 + 3) * 512);
        acc0 = __builtin_amdgcn_mfma_f32_16x16x32_f16(a, b0, acc0, 0, 0, 0);
        acc1 = __builtin_amdgcn_mfma_f32_16x16x32_f16(a, b1, acc1, 0, 0, 0);
        acc2 = __builtin_amdgcn_mfma_f32_16x16x32_f16(a, b2, acc2, 0, 0, 0);
        acc3 = __builtin_amdgcn_mfma_f32_16x16x32_f16(a, b3, acc3, 0, 0, 0);
    }
    float bv0 = b1l[sub], bv1 = b1l[16 + sub], bv2 = b1l[32 + sub], bv3 = b1l[48 + sub];
#pragma unroll
    for (int reg = 0; reg < 4; ++reg) {
        int r = quad * 4 + reg;
        __half* orow = h1 + (size_t)(tile * 16 + r) * 64;
        orow[sub]      = __float2half(fmaxf(acc0[reg] + bv0, 0.f));
        orow[16 + sub] = __float2half(fmaxf(acc1[reg] + bv1, 0.f));
        orow[32 + sub] = __float2half(fmaxf(acc2[reg] + bv2, 0.f));
        orow[48 + sub] = __float2half(fmaxf(acc3[reg] + bv3, 0.f));
    }
}

__global__ __launch_bounds__(256) void k_gemm2(
    const __half* __restrict__ zm2, const __half* __restrict__ h1,
    const __half* __restrict__ wbuf2, const float* __restrict__ b2l,
    const float* __restrict__ Wfc, const float* __restrict__ bfc,
    float* __restrict__ out, int ntiles) {
    int tile = blockIdx.x * 4 + (threadIdx.x >> 6);
    if (tile >= ntiles) return;
    int lane = threadIdx.x & 63;
    int sub = lane & 15;
    int quad = lane >> 4;
    int row = tile * 16 + sub;

    floatx4 acc0 = {0.f, 0.f, 0.f, 0.f};
    floatx4 acc1 = {0.f, 0.f, 0.f, 0.f};
    floatx4 acc2 = {0.f, 0.f, 0.f, 0.f};
    floatx4 acc3 = {0.f, 0.f, 0.f, 0.f};

    const _Float16* zrow = (const _Float16*)zm2 + (size_t)row * 64 + quad * 8;
    const _Float16* hrow = (const _Float16*)h1 + (size_t)row * 64 + quad * 8;
    const _Float16* wb = (const _Float16*)wbuf2 + (size_t)lane * 8;

    half8 amat[4];
    amat[0] = *(const half8*)(zrow);
    amat[1] = *(const half8*)(zrow + 32);
    amat[2] = *(const half8*)(hrow);
    amat[3] = *(const half8*)(hrow + 32);

#pragma unroll
    for (int ks = 0; ks < 4; ++ks) {
        half8 a = amat[ks];
        half8 b0 = *(const half8*)(wb + (size_t)(ks * 4 + 0) * 512);
        half8 b1 = *(const half8*)(wb + (size_t)(ks * 4 + 1) * 512);
        half8 b2 = *(const half8*)(wb + (size_t)(ks * 4 + 2) * 512);
        half8 b3 = *(const half8*)(wb + (size_t)(ks * 4 + 3) * 512);
        acc0 = __builtin_amdgcn_mfma_f32_16x16x32_f16(a, b0, acc0, 0, 0, 0);
        acc1 = __builtin_amdgcn_mfma_f32_16x16x32_f16(a, b1, acc1, 0, 0, 0);
        acc2 = __builtin_amdgcn_mfma_f32_16x16x32_f16(a, b2, acc2, 0, 0, 0);
        acc3 = __builtin_amdgcn_mfma_f32_16x16x32_f16(a, b3, acc3, 0, 0, 0);
    }
    float bb0 = b2l[sub], bb1 = b2l[16 + sub], bb2 = b2l[32 + sub], bb3 = b2l[48 + sub];
    float wv0 = Wfc[sub], wv1 = Wfc[16 + sub], wv2 = Wfc[32 + sub], wv3 = Wfc[48 + sub];
    float p[4];
#pragma unroll
    for (int reg = 0; reg < 4; ++reg) {
        p[reg] = fmaxf(acc0[reg] + bb0, 0.f) * wv0
               + fmaxf(acc1[reg] + bb1, 0.f) * wv1
               + fmaxf(acc2[reg] + bb2, 0.f) * wv2
               + fmaxf(acc3[reg] + bb3, 0.f) * wv3;
    }
#pragma unroll
    for (int m = 1; m <= 8; m <<= 1) {
#pragma unroll
        for (int reg = 0; reg < 4; ++reg) p[reg] += __shfl_xor(p[reg], m, 64);
    }
    if (sub == 0) {
        float b0 = bfc[0];
#pragma unroll
        for (int reg = 0; reg < 4; ++reg)
            out[tile * 16 + quad * 4 + reg] = p[reg] + b0;
    }
}

extern "C" void kernel_launch(void* const* d_in, const int* in_sizes, int n_in,
                              void* d_out, int out_size, void* d_ws, size_t ws_size,
                              hipStream_t stream) {
    const float* x   = (const float*)d_in[0];
    const int*   ei  = (const int*)d_in[1];
    const float* tau = (const float*)d_in[2];
    const float* W1l = (const float*)d_in[3];
    const float* b1l = (const float*)d_in[4];
    const float* W1r = (const float*)d_in[5];
    const float* W2l = (const float*)d_in[6];
    const float* b2l = (const float*)d_in[7];
    const float* W2r = (const float*)d_in[8];
    const float* Wfc = (const float*)d_in[9];
    const float* bfc = (const float*)d_in[10];
    float* out = (float*)d_out;

    const int N = in_sizes[0] / 64;   // 100000
    const int E = in_sizes[1] / 2;    // 3200000
    const int* src = ei;
    const int* dst = ei + E;

    char* w = (char*)d_ws;
    auto take = [&](size_t b) { char* p = w; w += (b + 255) & ~(size_t)255; return p; };
    int*    histT  = (int*)take((size_t)NBKT * NBLK * 4);
    int*    btot   = (int*)take((size_t)NBKT * 4);
    int*    bstart = (int*)take((size_t)(NBKT + 1) * 4);
    int*    binned = (int*)take((size_t)E * 4);
    int*    rowptr = (int*)take((size_t)N * 4);
    int*    deg    = (int*)take((size_t)N * 4);
    int*    colidx = (int*)take((size_t)E * 4);
    __half* xh     = (__half*)take((size_t)N * 64 * 2);    // 12.8 MB
    __half* h1     = (__half*)take((size_t)N * 64 * 2);    // 12.8 MB
    __half* zm1    = (__half*)take((size_t)N * 64 * 2);    // 12.8 MB
    __half* mt1    = (__half*)take((size_t)N * 2);
    __half* zm2    = (__half*)take((size_t)N * 64 * 2);    // 12.8 MB
    __half* wbuf1  = (__half*)take(1280 * 8 * 2);          // 20 KB
    __half* wbuf2  = (__half*)take(1024 * 8 * 2);          // 16 KB

    int n2 = N * 32;                  // half2 elements for prep
    int pblocks = 9 + (n2 + 255) / 256;
    int ntiles = N / 16;              // 6250 (exact)
    int gblocks = (ntiles + 3) / 4;   // 1563

    k_hist   <<<NBLK, 256, 0, stream>>>(dst, histT, E);
    k_scanblk<<<NBKT, NBLK, 0, stream>>>(histT, btot);
    k_scanbkt<<<1, 1024, 0, stream>>>(btot, bstart);
    k_scatter<<<NBLK, 256, 0, stream>>>(src, dst, histT, bstart, binned, E);
    k_bucket <<<NBKT, 256, 0, stream>>>(binned, bstart, rowptr, deg, colidx, N);
    k_prepall<<<pblocks, 256, 0, stream>>>(x, xh, n2, W1l, W1r, W2l, W2r, wbuf1, wbuf2);
    k_aggr1  <<<LAYER_GRID, LAYER_BLOCK, 0, stream>>>(xh, tau, rowptr, deg, colidx, zm1, mt1, N);
    k_gemm1  <<<gblocks, 256, 0, stream>>>(zm1, mt1, xh, tau, wbuf1, b1l, h1, ntiles);
    k_aggr2  <<<LAYER_GRID, LAYER_BLOCK, 0, stream>>>(h1, rowptr, deg, colidx, zm2, N);
    k_gemm2  <<<gblocks, 256, 0, stream>>>(zm2, h1, wbuf2, b2l, Wfc, bfc, out, ntiles);
}